// Round 1
// baseline (650.352 us; speedup 1.0000x reference)
//
#include <hip/hip_runtime.h>

#define B_ 512
#define L_ 512
#define N_ 128

// ---------------------------------------------------------------------------
// Kernel A: ET[i*N+j] = exp(trans[i*N+j])   (16384 elements)
// ---------------------------------------------------------------------------
__global__ void et_kernel(const float* __restrict__ trans, float* __restrict__ ET) {
    int x = blockIdx.x * 256 + threadIdx.x;
    ET[x] = __expf(trans[x]);
}

// ---------------------------------------------------------------------------
// Kernel B: per-batch path score
// path[b] = start_trans[t0] + em[b,0,t0] + sum_{t>=1} mask[b,t]*(trans[prev,cur]+em[b,t,cur])
// ---------------------------------------------------------------------------
__global__ __launch_bounds__(256) void path_kernel(
    const float* __restrict__ em, const int* __restrict__ tg,
    const float* __restrict__ mask, const float* __restrict__ st,
    const float* __restrict__ trans, float* __restrict__ path)
{
    const int b = blockIdx.x;
    const int tid = threadIdx.x;
    float acc = 0.f;
    for (int t = 1 + tid; t < L_; t += 256) {
        int cur  = tg[b * L_ + t];
        int prev = tg[b * L_ + t - 1];
        float inc = trans[prev * N_ + cur] + em[((size_t)b * L_ + t) * N_ + cur];
        acc += mask[b * L_ + t] * inc;
    }
    __shared__ float red[4];
    float v = acc;
#pragma unroll
    for (int off = 32; off >= 1; off >>= 1) v += __shfl_xor(v, off);
    if ((tid & 63) == 0) red[tid >> 6] = v;
    __syncthreads();
    if (tid == 0) {
        int t0 = tg[b * L_];
        float s0 = st[t0] + em[(size_t)b * L_ * N_ + t0];
        path[b] = red[0] + red[1] + red[2] + red[3] + s0;
    }
}

// ---------------------------------------------------------------------------
// Kernel C: per-batch forward-algorithm normalizer.
// One block (256 threads) per batch. Thread layout: jq = tid&31, h = tid>>5.
// Thread owns ET columns {jq, jq+32, jq+64, jq+96} for rows i in [h*16, h*16+16),
// held in registers (loaded once). Per step:
//   E[i] = exp(sc[i] - m_lag) (prev iter), matvec partials via registers+LDS E,
//   combine 8 h-partials, nxt = log(sum) + m_lag + em, mask-select, new E.
// Max is lagged by one step (safe: per-step score growth <= ~11 => exp <= e^11).
// ---------------------------------------------------------------------------
__global__ __launch_bounds__(256) void norm_kernel(
    const float* __restrict__ em, const float* __restrict__ mask,
    const float* __restrict__ st, const float* __restrict__ ET,
    float* __restrict__ norm)
{
    __shared__ float sc[N_];
    __shared__ __align__(16) float Ebuf[N_];
    __shared__ float part[8 * N_];
    __shared__ float wred[2];
    __shared__ float wsum[2];

    const int tid  = threadIdx.x;
    const int b    = blockIdx.x;
    const int jq   = tid & 31;
    const int h    = tid >> 5;   // 0..7
    const int lane = tid & 63;
    const int wid  = tid >> 6;

    // ET fragment into registers: et[q][k] = exp(trans[h*16+k][jq+32q])
    float et[4][16];
#pragma unroll
    for (int k = 0; k < 16; ++k) {
#pragma unroll
        for (int q = 0; q < 4; ++q) {
            et[q][k] = ET[(h * 16 + k) * N_ + jq + 32 * q];
        }
    }

    const size_t base = (size_t)b * L_ * N_;

    // ---- init: scores0 = start_trans + emission[:,0], exact max, E ----
    if (tid < N_) {
        float s = st[tid] + em[base + tid];
        sc[tid] = s;
        float wm = s;
#pragma unroll
        for (int off = 32; off >= 1; off >>= 1) wm = fmaxf(wm, __shfl_xor(wm, off));
        if (lane == 0) wred[wid] = wm;
    }
    __syncthreads();
    float m_prev = fmaxf(wred[0], wred[1]);
    if (tid < N_) Ebuf[tid] = __expf(sc[tid] - m_prev);

    // ---- scan ----
    for (int t = 1; t < L_; ++t) {
        __syncthreads();   // publishes Ebuf, sc, wred from previous phase
        float m_cur = fmaxf(wred[0], wred[1]);   // max of scores_{t-1}

        // prefetch this step's emission row + mask scalar (overlaps FMA phase)
        float em_v = 0.f;
        if (tid < N_) em_v = em[base + (size_t)t * N_ + tid];
        float mk = mask[b * L_ + t];

        // matvec partials: acc_q = sum_{i in h-range} E[i] * ET[i][jq+32q]
        float acc0 = 0.f, acc1 = 0.f, acc2 = 0.f, acc3 = 0.f;
        const float4* E4 = (const float4*)Ebuf;
#pragma unroll
        for (int kk = 0; kk < 4; ++kk) {
            float4 e4 = E4[h * 4 + kk];
            float ev[4] = {e4.x, e4.y, e4.z, e4.w};
#pragma unroll
            for (int c = 0; c < 4; ++c) {
                acc0 += ev[c] * et[0][kk * 4 + c];
                acc1 += ev[c] * et[1][kk * 4 + c];
                acc2 += ev[c] * et[2][kk * 4 + c];
                acc3 += ev[c] * et[3][kk * 4 + c];
            }
        }
        part[h * N_ + jq     ] = acc0;
        part[h * N_ + jq + 32] = acc1;
        part[h * N_ + jq + 64] = acc2;
        part[h * N_ + jq + 96] = acc3;
        __syncthreads();   // publishes part

        if (tid < N_) {
            float s = 0.f;
#pragma unroll
            for (int hh = 0; hh < 8; ++hh) s += part[hh * N_ + tid];
            float nxt = __logf(s) + m_prev + em_v;
            float old = sc[tid];
            float ns  = mk * nxt + (1.f - mk) * old;
            sc[tid]   = ns;
            Ebuf[tid] = __expf(ns - m_cur);
            float wm = ns;
#pragma unroll
            for (int off = 32; off >= 1; off >>= 1) wm = fmaxf(wm, __shfl_xor(wm, off));
            if (lane == 0) wred[wid] = wm;
        }
        m_prev = m_cur;
    }

    // ---- final logsumexp over states (exact max available in wred) ----
    __syncthreads();
    float m_f = fmaxf(wred[0], wred[1]);
    if (tid < N_) {
        float v = __expf(sc[tid] - m_f);
#pragma unroll
        for (int off = 32; off >= 1; off >>= 1) v += __shfl_xor(v, off);
        if (lane == 0) wsum[wid] = v;
    }
    __syncthreads();
    if (tid == 0) norm[b] = m_f + __logf(wsum[0] + wsum[1]);
}

// ---------------------------------------------------------------------------
// Kernel D: out = mean_b(norm[b] - path[b])
// ---------------------------------------------------------------------------
__global__ __launch_bounds__(256) void final_kernel(
    const float* __restrict__ norm, const float* __restrict__ path,
    float* __restrict__ out)
{
    const int tid = threadIdx.x;
    float v = 0.f;
    for (int i = tid; i < B_; i += 256) v += norm[i] - path[i];
#pragma unroll
    for (int off = 32; off >= 1; off >>= 1) v += __shfl_xor(v, off);
    __shared__ float red[4];
    if ((tid & 63) == 0) red[tid >> 6] = v;
    __syncthreads();
    if (tid == 0) out[0] = (red[0] + red[1] + red[2] + red[3]) / (float)B_;
}

// ---------------------------------------------------------------------------
extern "C" void kernel_launch(void* const* d_in, const int* in_sizes, int n_in,
                              void* d_out, int out_size, void* d_ws, size_t ws_size,
                              hipStream_t stream) {
    const float* emission    = (const float*)d_in[0];
    const int*   target      = (const int*)  d_in[1];
    const float* mask        = (const float*)d_in[2];
    const float* start_trans = (const float*)d_in[3];
    const float* trans       = (const float*)d_in[4];
    float* out = (float*)d_out;

    float* ws_f  = (float*)d_ws;
    float* ET    = ws_f;            // 16384 floats
    float* path  = ws_f + 16384;    // 512 floats
    float* norm  = ws_f + 16896;    // 512 floats

    et_kernel   <<<N_ * N_ / 256, 256, 0, stream>>>(trans, ET);
    path_kernel <<<B_, 256, 0, stream>>>(emission, target, mask, start_trans, trans, path);
    norm_kernel <<<B_, 256, 0, stream>>>(emission, mask, start_trans, ET, norm);
    final_kernel<<<1, 256, 0, stream>>>(norm, path, out);
}

// Round 2
// 479.715 us; speedup vs baseline: 1.3557x; 1.3557x over previous
//
#include <hip/hip_runtime.h>

#define B_ 512
#define L_ 512
#define N_ 128
#define C_BIAS 3.0f

typedef _Float16 h2_t __attribute__((ext_vector_type(2)));

__device__ __forceinline__ float dot2f(h2_t a, h2_t b, float c) {
#if __has_builtin(__builtin_amdgcn_fdot2)
    return __builtin_amdgcn_fdot2(a, b, c, false);
#else
    return c + (float)a[0] * (float)b[0] + (float)a[1] * (float)b[1];
#endif
}

// ---------------------------------------------------------------------------
// norm_kernel: one block (256 thr) per batch.
// Wave w owns j in [32w,32w+32). lane l: jq=l&31, ih=l>>5 -> j=(w<<5)|jq,
// i-range [64*ih, 64*ih+64). ET column fragment (64 rows as 32 half2) lives in
// registers for all 512 steps. Scores ns[j] live in registers (duplicated in
// the ih pair). Per step:
//   barrier A -> (a) 5-step shfl max of ns_{t-1} -> wred[w]  [off critical path]
//               (b) 8x ds_read_b128 of E (f16) + 32x v_dot2  -> s
//   s += shfl_xor(s,32)  (pair combine)
//   barrier B -> read wred (M_{t-1}); nxt = log(s)+M_norm+C+em; mask-select;
//   E_t = exp(ns - M_{t-1} - C) f16 -> LDS (ih==0 lanes).
// M_norm (used to write E_{t-1}) is carried in a register => recovery exact.
// Path score for the same batch is folded into the init phase.
// ---------------------------------------------------------------------------
__global__ __launch_bounds__(256) void norm_kernel(
    const float* __restrict__ em, const int* __restrict__ tg,
    const float* __restrict__ mask, const float* __restrict__ st,
    const float* __restrict__ trans,
    float* __restrict__ norm_out, float* __restrict__ path_out)
{
    __shared__ __align__(16) _Float16 Eh[N_];
    __shared__ __align__(16) float wred[4];
    __shared__ __align__(16) float wsum[4];
    __shared__ float pred[4];

    const int tid = threadIdx.x;
    const int b   = blockIdx.x;
    const int w   = tid >> 6;
    const int l   = tid & 63;
    const int jq  = l & 31;
    const int ih  = l >> 5;
    const int j   = (w << 5) | jq;
    const int i0  = ih * 64;
    const size_t base = (size_t)b * L_ * N_;

    // ---- path score partials (independent; overlaps ET-load latency) ----
    float pacc = 0.f;
    for (int t = 1 + tid; t < L_; t += 256) {
        int cur  = tg[b * L_ + t];
        int prev = tg[b * L_ + t - 1];
        pacc += mask[b * L_ + t] * (trans[prev * N_ + cur] + em[base + (size_t)t * N_ + cur]);
    }
#pragma unroll
    for (int off = 32; off >= 1; off >>= 1) pacc += __shfl_xor(pacc, off);
    if (l == 0) pred[w] = pacc;

    // ---- ET column fragment into registers (rows i0..i0+63, col j) ----
    h2_t et2[32];
#pragma unroll
    for (int k = 0; k < 32; ++k) {
        float f0 = __expf(trans[(i0 + 2 * k    ) * N_ + j]);
        float f1 = __expf(trans[(i0 + 2 * k + 1) * N_ + j]);
        h2_t e; e[0] = (_Float16)f0; e[1] = (_Float16)f1;
        et2[k] = e;
    }

    // ---- init: ns_0 = start + em[:,0]; exact max M_0; E_0 ----
    float ns = st[j] + em[base + j];
    {
        float mx = ns;
#pragma unroll
        for (int off = 16; off >= 1; off >>= 1) mx = fmaxf(mx, __shfl_xor(mx, off));
        if (l == 0) wred[w] = mx;
    }
    __syncthreads();
    if (tid == 0) {
        int t0 = tg[b * L_];
        path_out[b] = pred[0] + pred[1] + pred[2] + pred[3] + st[t0] + em[base + t0];
    }
    float4 wr0 = *(float4*)wred;
    float M_norm = fmaxf(fmaxf(wr0.x, wr0.y), fmaxf(wr0.z, wr0.w));
    if (ih == 0) Eh[j] = (_Float16)__expf(ns - M_norm - C_BIAS);

    // prefetch step-1 emission/mask
    float em_cur = em[base + N_ + j];
    float mk_cur = mask[b * L_ + 1];

    // ---- scan ----
    for (int t = 1; t < L_; ++t) {
        __syncthreads();   // A: Eh (and wred-read completion) published

        // prefetch t+1 (full step to hide HBM/L2 latency)
        int tn = (t + 1 < L_) ? t + 1 : t;
        float em_nxt = em[base + (size_t)tn * N_ + j];
        float mk_nxt = mask[b * L_ + tn];

        // max chain of ns_{t-1} (register-only, overlaps dot phase)
        float mx = ns;
#pragma unroll
        for (int off = 16; off >= 1; off >>= 1) mx = fmaxf(mx, __shfl_xor(mx, off));
        if (l == 0) wred[w] = mx;

        // dot phase: s = sum_i E[i] * ET[i][j] over this lane's 64 rows
        const float4* E4 = (const float4*)Eh + ih * 8;
        float s = 0.f;
#pragma unroll
        for (int r = 0; r < 8; ++r) {
            float4 blk = E4[r];
            const h2_t* e2 = (const h2_t*)&blk;
            s = dot2f(e2[0], et2[r * 4 + 0], s);
            s = dot2f(e2[1], et2[r * 4 + 1], s);
            s = dot2f(e2[2], et2[r * 4 + 2], s);
            s = dot2f(e2[3], et2[r * 4 + 3], s);
        }
        s += __shfl_xor(s, 32);   // combine the ih pair -> full column sum

        __syncthreads();   // B: wred published
        float4 wr = *(float4*)wred;
        float M_new = fmaxf(fmaxf(wr.x, wr.y), fmaxf(wr.z, wr.w));  // max ns_{t-1}

        float nxt = __logf(s) + (M_norm + C_BIAS) + em_cur;
        ns = mk_cur * nxt + (1.f - mk_cur) * ns;

        M_norm = M_new;
        if (ih == 0) Eh[j] = (_Float16)__expf(ns - M_norm - C_BIAS);

        em_cur = em_nxt;
        mk_cur = mk_nxt;
    }

    // ---- final logsumexp over states ----
    {
        float mx = ns;
#pragma unroll
        for (int off = 16; off >= 1; off >>= 1) mx = fmaxf(mx, __shfl_xor(mx, off));
        if (l == 0) wred[w] = mx;
    }
    __syncthreads();
    float4 wrf = *(float4*)wred;
    float M_f = fmaxf(fmaxf(wrf.x, wrf.y), fmaxf(wrf.z, wrf.w));
    float v = (ih == 0) ? __expf(ns - M_f) : 0.f;
#pragma unroll
    for (int off = 32; off >= 1; off >>= 1) v += __shfl_xor(v, off);
    if (l == 0) wsum[w] = v;
    __syncthreads();
    if (tid == 0) norm_out[b] = M_f + __logf(wsum[0] + wsum[1] + wsum[2] + wsum[3]);
}

// ---------------------------------------------------------------------------
__global__ __launch_bounds__(256) void final_kernel(
    const float* __restrict__ norm, const float* __restrict__ path,
    float* __restrict__ out)
{
    const int tid = threadIdx.x;
    float v = 0.f;
    for (int i = tid; i < B_; i += 256) v += norm[i] - path[i];
#pragma unroll
    for (int off = 32; off >= 1; off >>= 1) v += __shfl_xor(v, off);
    __shared__ float red[4];
    if ((tid & 63) == 0) red[tid >> 6] = v;
    __syncthreads();
    if (tid == 0) out[0] = (red[0] + red[1] + red[2] + red[3]) / (float)B_;
}

// ---------------------------------------------------------------------------
extern "C" void kernel_launch(void* const* d_in, const int* in_sizes, int n_in,
                              void* d_out, int out_size, void* d_ws, size_t ws_size,
                              hipStream_t stream) {
    const float* emission    = (const float*)d_in[0];
    const int*   target      = (const int*)  d_in[1];
    const float* mask        = (const float*)d_in[2];
    const float* start_trans = (const float*)d_in[3];
    const float* trans       = (const float*)d_in[4];
    float* out = (float*)d_out;

    float* ws_f  = (float*)d_ws;
    float* path  = ws_f;          // 512 floats
    float* norm  = ws_f + 512;    // 512 floats

    norm_kernel <<<B_, 256, 0, stream>>>(emission, target, mask, start_trans, trans, norm, path);
    final_kernel<<<1, 256, 0, stream>>>(norm, path, out);
}